// Round 1
// baseline (374.369 us; speedup 1.0000x reference)
//
#include <hip/hip_runtime.h>

typedef __attribute__((ext_vector_type(8))) short short8v;   // 8 bf16 (4 VGPRs)
typedef __attribute__((ext_vector_type(4))) float f32x4;     // MFMA accumulator

#define N_ROWS 8192
#define KSPLIT 768          // 3 x 256 (hi|lo|hi concatenation)
#define SEP 64

// ---------- helpers ----------
__device__ inline unsigned f2ord(float x){
  unsigned u = __float_as_uint(x);
  return (u & 0x80000000u) ? ~u : (u | 0x80000000u);   // monotone f32 -> u32
}
__device__ inline float ord2f(unsigned u){
  unsigned b = (u & 0x80000000u) ? (u & 0x7fffffffu) : ~u;
  return __uint_as_float(b);
}
__device__ inline unsigned short bf16rn(float x){
  unsigned b = __float_as_uint(x);
  unsigned r = (b + 0x7fffu + ((b >> 16) & 1u)) >> 16;  // round-to-nearest-even
  return (unsigned short)r;
}
__device__ inline void gload16(const void* g, void* l){
  __builtin_amdgcn_global_load_lds((const __attribute__((address_space(1))) void*)g,
                                   (__attribute__((address_space(3))) void*)l, 16, 0, 0);
}

// ---------- K0: split f32 -> bf16 hi/lo, K-concatenated ----------
// cur2  = [hi | lo | hi]  (8192 x 768 bf16)
// prev2 = [hi | hi | lo]
// => sum over K=768 gives hi*hi + lo*hi + hi*lo (drops only lo*lo ~1e-4)
__global__ void split_kernel(const float* __restrict__ cur, const float* __restrict__ prev,
                             unsigned short* __restrict__ cur2, unsigned short* __restrict__ prev2){
  int g = blockIdx.x * blockDim.x + threadIdx.x;         // 0 .. 2*524288-1
  int isB = (g >= (N_ROWS * 256 / 4)) ? 1 : 0;
  int t = g - isB * (N_ROWS * 256 / 4);
  const float4 v = ((const float4*)(isB ? prev : cur))[t];
  int row = t >> 6;                                      // 64 float4 per 256-col row
  int col = (t & 63) << 2;
  float xs[4] = {v.x, v.y, v.z, v.w};
  unsigned short h[4], l[4];
  #pragma unroll
  for (int j = 0; j < 4; ++j){
    unsigned short hb = bf16rn(xs[j]);
    float hf = __uint_as_float(((unsigned)hb) << 16);
    h[j] = hb;
    l[j] = bf16rn(xs[j] - hf);                           // exact residual capture
  }
  unsigned short* dst = isB ? prev2 : cur2;
  size_t base = (size_t)row * KSPLIT + col;
  uint2 hw, lw;
  hw.x = (unsigned)h[0] | ((unsigned)h[1] << 16); hw.y = (unsigned)h[2] | ((unsigned)h[3] << 16);
  lw.x = (unsigned)l[0] | ((unsigned)l[1] << 16); lw.y = (unsigned)l[2] | ((unsigned)l[3] << 16);
  *(uint2*)(dst + base) = hw;
  if (!isB){
    *(uint2*)(dst + base + 256) = lw;
    *(uint2*)(dst + base + 512) = hw;
  } else {
    *(uint2*)(dst + base + 256) = hw;
    *(uint2*)(dst + base + 512) = lw;
  }
}

// ---------- GEMM: 128x128 tile, 4 waves (2x2), 16x16x32 bf16 MFMA ----------
// EPI 0: min/max only; EPI 1: min/max + store M; EPI 2: histogram (reads mm)
template<int EPI>
__global__ __launch_bounds__(256) void gemm_kernel(const unsigned short* __restrict__ A2,
                                                   const unsigned short* __restrict__ B2,
                                                   float* __restrict__ Mout,
                                                   unsigned* __restrict__ mm,
                                                   unsigned* __restrict__ hist){
  __shared__ unsigned short As[128 * 32];
  __shared__ unsigned short Bs[128 * 32];
  __shared__ float red[8];
  __shared__ unsigned lh[SEP];

  const int tid  = threadIdx.x;
  const int lane = tid & 63;
  const int wave = tid >> 6;
  const int bm = blockIdx.x >> 6;
  const int bn = blockIdx.x & 63;
  const int wr = wave >> 1, wc = wave & 1;

  const size_t aBase = (size_t)bm * 128 * KSPLIT;
  const size_t bBase = (size_t)bn * 128 * KSPLIT;
  const int id0 = tid, id1 = tid + 256;                  // 512 x 16B chunks per tile
  const size_t aOff0 = aBase + (size_t)(id0 >> 2) * KSPLIT + (id0 & 3) * 8;
  const size_t aOff1 = aBase + (size_t)(id1 >> 2) * KSPLIT + (id1 & 3) * 8;
  const size_t bOff0 = bBase + (size_t)(id0 >> 2) * KSPLIT + (id0 & 3) * 8;
  const size_t bOff1 = bBase + (size_t)(id1 >> 2) * KSPLIT + (id1 & 3) * 8;

  f32x4 acc[4][4];
  #pragma unroll
  for (int m = 0; m < 4; ++m)
    #pragma unroll
    for (int n = 0; n < 4; ++n)
      acc[m][n] = (f32x4){0.f, 0.f, 0.f, 0.f};

  const int rsel = lane & 15;
  const int ksel = (lane >> 4) * 8;

  for (int ks = 0; ks < KSPLIT / 32; ++ks){
    const int k0 = ks * 32;
    gload16(A2 + aOff0 + k0, As + id0 * 8);
    gload16(A2 + aOff1 + k0, As + id1 * 8);
    gload16(B2 + bOff0 + k0, Bs + id0 * 8);
    gload16(B2 + bOff1 + k0, Bs + id1 * 8);
    __syncthreads();
    short8v a[4], b[4];
    #pragma unroll
    for (int m = 0; m < 4; ++m)
      a[m] = *(const short8v*)(As + (wr * 64 + m * 16 + rsel) * 32 + ksel);
    #pragma unroll
    for (int n = 0; n < 4; ++n)
      b[n] = *(const short8v*)(Bs + (wc * 64 + n * 16 + rsel) * 32 + ksel);
    #pragma unroll
    for (int m = 0; m < 4; ++m)
      #pragma unroll
      for (int n = 0; n < 4; ++n)
        acc[m][n] = __builtin_amdgcn_mfma_f32_16x16x32_bf16(a[m], b[n], acc[m][n], 0, 0, 0);
    __syncthreads();
  }

  if (EPI == 0 || EPI == 1){
    float mn = 3.4e38f, mx = -3.4e38f;
    const size_t sbase = (((size_t)blockIdx.x * 4 + wave) * 16) * 256 + (size_t)lane * 4;
    #pragma unroll
    for (int m = 0; m < 4; ++m){
      #pragma unroll
      for (int n = 0; n < 4; ++n){
        #pragma unroll
        for (int q = 0; q < 4; ++q){
          float v = acc[m][n][q];
          mn = fminf(mn, v); mx = fmaxf(mx, v);
        }
        if (EPI == 1)
          *(f32x4*)(Mout + sbase + (size_t)(m * 4 + n) * 256) = acc[m][n];
      }
    }
    #pragma unroll
    for (int off = 32; off; off >>= 1){
      mn = fminf(mn, __shfl_xor(mn, off));
      mx = fmaxf(mx, __shfl_xor(mx, off));
    }
    if (lane == 0){ red[wave] = mn; red[4 + wave] = mx; }
    __syncthreads();
    if (tid == 0){
      mn = fminf(fminf(red[0], red[1]), fminf(red[2], red[3]));
      mx = fmaxf(fmaxf(red[4], red[5]), fmaxf(red[6], red[7]));
      atomicMin(mm + 0, f2ord(mn));
      atomicMax(mm + 1, f2ord(mx));
    }
  }
  if (EPI == 2){
    if (tid < SEP) lh[tid] = 0u;
    __syncthreads();
    const float mnv = ord2f(mm[0]);
    const float mxv = ord2f(mm[1]);
    const float interval = (mxv - mnv) / 64.0f;          // matches reference exactly
    #pragma unroll
    for (int m = 0; m < 4; ++m)
      #pragma unroll
      for (int n = 0; n < 4; ++n)
        #pragma unroll
        for (int q = 0; q < 4; ++q){
          float r = (acc[m][n][q] - mnv) / interval;     // true division, like ref
          int i = (int)floorf(r);
          i = i < 0 ? 0 : (i > 63 ? 63 : i);
          atomicAdd(&lh[i], 1u);
        }
    __syncthreads();
    if (tid < SEP){ unsigned c = lh[tid]; if (c) atomicAdd(hist + tid, c); }
  }
}

// ---------- histogram from stored M ----------
__global__ __launch_bounds__(256) void hist_ws_kernel(const float4* __restrict__ Mv,
                                                      const unsigned* __restrict__ mm,
                                                      unsigned* __restrict__ hist){
  __shared__ unsigned lh[SEP];
  const int tid = threadIdx.x;
  if (tid < SEP) lh[tid] = 0u;
  __syncthreads();
  const float mnv = ord2f(mm[0]);
  const float mxv = ord2f(mm[1]);
  const float interval = (mxv - mnv) / 64.0f;
  size_t g = (size_t)blockIdx.x * 256 + tid;
  const size_t stride = (size_t)gridDim.x * 256;
  for (size_t i = g; i < (size_t)16777216; i += stride){ // 16M float4 = 64M f32
    float4 v = Mv[i];
    float vs[4] = {v.x, v.y, v.z, v.w};
    #pragma unroll
    for (int q = 0; q < 4; ++q){
      float r = (vs[q] - mnv) / interval;
      int b = (int)floorf(r);
      b = b < 0 ? 0 : (b > 63 ? 63 : b);
      atomicAdd(&lh[b], 1u);
    }
  }
  __syncthreads();
  if (tid < SEP){ unsigned c = lh[tid]; if (c) atomicAdd(hist + tid, c); }
}

// ---------- finalize: out = sigmoid( sum_j sigmoid(count_j) * W_j ) ----------
__global__ void fin_kernel(const unsigned* __restrict__ hist, const float* __restrict__ W,
                           float* __restrict__ out){
  int j = threadIdx.x;                                   // 64 threads = 1 wave
  float beta = 1.f / (1.f + expf(-(float)hist[j]));
  float p = beta * W[j];
  #pragma unroll
  for (int off = 32; off; off >>= 1) p += __shfl_down(p, off);
  if (j == 0) out[0] = 1.f / (1.f + expf(-p));
}

extern "C" void kernel_launch(void* const* d_in, const int* in_sizes, int n_in,
                              void* d_out, int out_size, void* d_ws, size_t ws_size,
                              hipStream_t stream){
  const float* cur  = (const float*)d_in[0];
  const float* prev = (const float*)d_in[1];
  const float* W    = (const float*)d_in[2];
  float* out = (float*)d_out;
  char* ws = (char*)d_ws;

  // ws layout
  unsigned short* cur2  = (unsigned short*)ws;                 // 12,582,912 B
  unsigned short* prev2 = (unsigned short*)(ws + 12582912);    // 12,582,912 B
  unsigned* mm   = (unsigned*)(ws + 25165824);                 // [min,max] ordered-u32
  unsigned* hist = (unsigned*)(ws + 25165832);                 // 64 x u32
  float* Mbuf    = (float*)(ws + 25166336);                    // 268,435,456 B (optional)

  const int storeOK = (ws_size >= (size_t)25166336 + (size_t)268435456) ? 1 : 0;

  // init atomics + hist (ws is poisoned 0xAA before every call)
  hipMemsetAsync(mm, 0xFF, 4, stream);                         // min <- +max order
  hipMemsetAsync((char*)mm + 4, 0, 4 + 256, stream);           // max + hist <- 0

  split_kernel<<<4096, 256, 0, stream>>>(cur, prev, cur2, prev2);

  if (storeOK){
    gemm_kernel<1><<<4096, 256, 0, stream>>>(cur2, prev2, Mbuf, mm, hist);
    hist_ws_kernel<<<2048, 256, 0, stream>>>((const float4*)Mbuf, mm, hist);
  } else {
    gemm_kernel<0><<<4096, 256, 0, stream>>>(cur2, prev2, Mbuf, mm, hist);
    gemm_kernel<2><<<4096, 256, 0, stream>>>(cur2, prev2, Mbuf, mm, hist);
  }

  fin_kernel<<<1, 64, 0, stream>>>(hist, W, out);
}